// Round 1
// baseline (247.209 us; speedup 1.0000x reference)
//
#include <hip/hip_runtime.h>

#define BATCH 4
#define CIN 64
#define H 128
#define W 128
#define COUT 64
#define KK 9
#define HO 128
#define WO 128
#define NPIX (HO*WO)
#define TILE 128     // one output row per block
#define CB 4         // channels per chunk
#define NSLOT (KK*TILE)   // 1152 sample slots per block

// Transpose weight [COUT][CIN*9] -> Wt[r][COUT] with r = c*9+k (576 x 64)
__global__ void wt_kernel(const float* __restrict__ w, float* __restrict__ wt) {
    int g = blockIdx.x * 256 + threadIdx.x;   // 0..36863
    int o = g & 63;
    int r = g >> 6;                            // 0..575
    wt[g] = w[o * 576 + r];
}

__global__ __launch_bounds__(256, 2)
void dcn_main(const float* __restrict__ x, const float* __restrict__ offs,
              const float* __restrict__ mask, const float* __restrict__ wt,
              const float* __restrict__ bias, float* __restrict__ out) {
    const int blk = blockIdx.x;      // 0..511
    const int b  = blk >> 7;         // batch
    const int oy = blk & 127;        // output row
    const int tid = threadIdx.x;

    __shared__ __align__(16) float Wl[36 * 64];        // 9.2 KB
    __shared__ __align__(16) float Sl[CB * KK * TILE]; // 18 KB

    // ---- Phase 1: per-slot sample descriptors (kept in registers) ----
    int   i00[5], i01[5], i10[5], i11[5];
    float w00[5], w01[5], w10[5], w11[5];
    int   sk[5], sox[5];
    bool  slive[5];

    #pragma unroll
    for (int i = 0; i < 5; ++i) {
        int s = tid + i * 256;
        bool live = (s < NSLOT);
        int ss = live ? s : 0;
        int k  = ss >> 7;            // 0..8
        int ox = ss & 127;
        sk[i] = k; sox[i] = ox; slive[i] = live;
        int kh = k / 3, kw = k - kh * 3;

        float offy = offs[((b * (2*KK) + 2*k    ) * HO + oy) * WO + ox];
        float offx = offs[((b * (2*KK) + 2*k + 1) * HO + oy) * WO + ox];
        float m    = mask[((b * KK + k) * HO + oy) * WO + ox];

        float py = (float)(oy - 1 + kh) + offy;
        float px = (float)(ox - 1 + kw) + offx;
        float fy = floorf(py), fx = floorf(px);
        float ly = py - fy, lx = px - fx;
        int y0 = (int)fy, x0 = (int)fx;
        int y1 = y0 + 1, x1 = x0 + 1;

        float v00 = (y0 >= 0 && y0 < H && x0 >= 0 && x0 < W) ? 1.f : 0.f;
        float v01 = (y0 >= 0 && y0 < H && x1 >= 0 && x1 < W) ? 1.f : 0.f;
        float v10 = (y1 >= 0 && y1 < H && x0 >= 0 && x0 < W) ? 1.f : 0.f;
        float v11 = (y1 >= 0 && y1 < H && x1 >= 0 && x1 < W) ? 1.f : 0.f;

        int y0c = min(max(y0, 0), H-1), y1c = min(max(y1, 0), H-1);
        int x0c = min(max(x0, 0), W-1), x1c = min(max(x1, 0), W-1);

        i00[i] = y0c * W + x0c;  i01[i] = y0c * W + x1c;
        i10[i] = y1c * W + x0c;  i11[i] = y1c * W + x1c;

        float live_f = live ? m : 0.f;
        w00[i] = (1.f - ly) * (1.f - lx) * live_f * v00;
        w01[i] = (1.f - ly) * lx         * live_f * v01;
        w10[i] = ly         * (1.f - lx) * live_f * v10;
        w11[i] = ly         * lx         * live_f * v11;
    }

    // ---- Main loop over channel chunks ----
    float acc[4][8];
    #pragma unroll
    for (int a = 0; a < 4; ++a)
        #pragma unroll
        for (int j = 0; j < 8; ++j) acc[a][j] = 0.f;

    const int pg = tid & 15;    // pixel group: pixels pg*8 .. pg*8+7
    const int og = tid >> 4;    // cout group: couts og*4 .. og*4+3

    for (int cc = 0; cc < CIN / CB; ++cc) {
        const int c0 = cc * CB;
        __syncthreads();   // protect LDS from previous iteration's readers

        // stage transposed-weight chunk (rows c0*9 .. c0*9+36 are contiguous)
        const float* wsrc = wt + c0 * 9 * 64;
        #pragma unroll
        for (int j = 0; j < 9; ++j) Wl[tid + j * 256] = wsrc[tid + j * 256];

        // gather samples for CB channels into LDS
        #pragma unroll
        for (int i = 0; i < 5; ++i) {
            #pragma unroll
            for (int ci = 0; ci < CB; ++ci) {
                const float* xb = x + (size_t)((b * CIN + c0 + ci) * (H * W));
                float v = w00[i] * xb[i00[i]] + w01[i] * xb[i01[i]]
                        + w10[i] * xb[i10[i]] + w11[i] * xb[i11[i]];
                if (slive[i]) Sl[(ci * KK + sk[i]) * TILE + sox[i]] = v;
            }
        }
        __syncthreads();

        // register-blocked outer-product GEMM over 36 reduction rows
        #pragma unroll 4
        for (int r = 0; r < 36; ++r) {
            float4 wv = *(const float4*)&Wl[r * 64 + og * 4];
            float4 s0 = *(const float4*)&Sl[r * TILE + pg * 8];
            float4 s1 = *(const float4*)&Sl[r * TILE + pg * 8 + 4];
            #pragma unroll
            for (int a = 0; a < 4; ++a) {
                float wa = (a == 0) ? wv.x : (a == 1) ? wv.y : (a == 2) ? wv.z : wv.w;
                acc[a][0] += wa * s0.x;  acc[a][1] += wa * s0.y;
                acc[a][2] += wa * s0.z;  acc[a][3] += wa * s0.w;
                acc[a][4] += wa * s1.x;  acc[a][5] += wa * s1.y;
                acc[a][6] += wa * s1.z;  acc[a][7] += wa * s1.w;
            }
        }
    }

    // ---- Epilogue ----
    const int px0 = pg * 8;
    #pragma unroll
    for (int a = 0; a < 4; ++a) {
        int o = og * 4 + a;
        float bv = bias[o];
        float* dst = out + (size_t)(((b * COUT + o) * HO + oy) * WO + px0);
        float4 v0 = make_float4(acc[a][0] + bv, acc[a][1] + bv,
                                acc[a][2] + bv, acc[a][3] + bv);
        float4 v1 = make_float4(acc[a][4] + bv, acc[a][5] + bv,
                                acc[a][6] + bv, acc[a][7] + bv);
        *(float4*)dst = v0;
        *(float4*)(dst + 4) = v1;
    }
}

extern "C" void kernel_launch(void* const* d_in, const int* in_sizes, int n_in,
                              void* d_out, int out_size, void* d_ws, size_t ws_size,
                              hipStream_t stream) {
    const float* x    = (const float*)d_in[0];
    const float* offs = (const float*)d_in[1];
    const float* mask = (const float*)d_in[2];
    const float* w    = (const float*)d_in[3];
    const float* bias = (const float*)d_in[4];
    float* out = (float*)d_out;
    float* wt  = (float*)d_ws;   // 576*64 floats = 147456 bytes

    hipLaunchKernelGGL(wt_kernel, dim3(144), dim3(256), 0, stream, w, wt);
    hipLaunchKernelGGL(dcn_main, dim3(BATCH * HO), dim3(256), 0, stream,
                       x, offs, mask, wt, bias, out);
}

// Round 2
// 245.723 us; speedup vs baseline: 1.0060x; 1.0060x over previous
//
#include <hip/hip_runtime.h>

#define BATCH 4
#define CIN 64
#define H 128
#define W 128
#define COUT 64
#define KK 9
#define HO 128
#define WO 128

// Transpose weight [COUT][CIN*9] -> Wt[r][COUT], r = c*9+k  (576 x 64)
__global__ void wt_kernel(const float* __restrict__ w, float* __restrict__ wt) {
    int g = blockIdx.x * 256 + threadIdx.x;   // 0..36863
    int o = g & 63;
    int r = g >> 6;
    wt[g] = w[o * 576 + r];
}

// One k-range pass: compute bilinear descriptors for k in [KBASE, KBASE+KR),
// then accumulate over this wave's 16 channels into acc[64].
template <int KBASE, int KR>
__device__ __forceinline__ void dcn_pass(
    const float* __restrict__ x, const float* __restrict__ offs,
    const float* __restrict__ mask, const float* __restrict__ wt,
    int b, int oy, int ox, int wid, float acc[64])
{
    int   off00[KR], d1_[KR], d2_[KR];
    float w00_[KR], w01_[KR], w10_[KR], w11_[KR];

    #pragma unroll
    for (int kk = 0; kk < KR; ++kk) {
        const int k = KBASE + kk;
        const int kh = k / 3, kw = k - kh * 3;

        float offy = offs[(((b * (2*KK)) + 2*k    ) * HO + oy) * WO + ox];
        float offx = offs[(((b * (2*KK)) + 2*k + 1) * HO + oy) * WO + ox];
        float m    = mask[(((b * KK) + k) * HO + oy) * WO + ox];

        float py = (float)(oy - 1 + kh) + offy;
        float px = (float)(ox - 1 + kw) + offx;
        float fy = floorf(py), fx = floorf(px);
        float ly = py - fy, lx = px - fx;
        int y0 = (int)fy, x0 = (int)fx;
        int y1 = y0 + 1, x1 = x0 + 1;

        bool y0v = (y0 >= 0) & (y0 < H);
        bool y1v = (y1 >= 0) & (y1 < H);
        bool x0v = (x0 >= 0) & (x0 < W);
        bool x1v = (x1 >= 0) & (x1 < W);

        int y0c = min(max(y0, 0), H-1), y1c = min(max(y1, 0), H-1);
        int x0c = min(max(x0, 0), W-1), x1c = min(max(x1, 0), W-1);

        off00[kk] = y0c * W + x0c;
        d1_[kk]   = x1c - x0c;            // 0 or 1
        d2_[kk]   = (y1c - y0c) * W;      // 0 or W

        w00_[kk] = (1.f - ly) * (1.f - lx) * m * ((y0v & x0v) ? 1.f : 0.f);
        w01_[kk] = (1.f - ly) * lx         * m * ((y0v & x1v) ? 1.f : 0.f);
        w10_[kk] = ly         * (1.f - lx) * m * ((y1v & x0v) ? 1.f : 0.f);
        w11_[kk] = ly         * lx         * m * ((y1v & x1v) ? 1.f : 0.f);
    }

    const float* xw = x + ((size_t)(b * CIN + wid * 16) << 14);
    for (int ci = 0; ci < 16; ++ci) {
        const float* xb = xw + ((size_t)ci << 14);
        const float* wr = wt + (size_t)(((wid * 16 + ci) * KK + KBASE) * COUT);
        #pragma unroll
        for (int kk = 0; kk < KR; ++kk) {
            int o00 = off00[kk];
            float v00 = xb[o00];
            float v01 = xb[o00 + d1_[kk]];
            float v10 = xb[o00 + d2_[kk]];
            float v11 = xb[o00 + d1_[kk] + d2_[kk]];
            float v = fmaf(w00_[kk], v00,
                      fmaf(w01_[kk], v01,
                      fmaf(w10_[kk], v10, w11_[kk] * v11)));
            const float* wrow = wr + kk * COUT;   // wave-uniform -> s_load
            #pragma unroll
            for (int o = 0; o < COUT; ++o)
                acc[o] = fmaf(v, wrow[o], acc[o]);
        }
    }
}

__global__ __launch_bounds__(256, 4)
void dcn_main(const float* __restrict__ x, const float* __restrict__ offs,
              const float* __restrict__ mask, const float* __restrict__ wt,
              const float* __restrict__ bias, float* __restrict__ out) {
    const int blk  = blockIdx.x;          // 0..1023
    const int tid  = threadIdx.x;
    const int lane = tid & 63;
    const int wid  = __builtin_amdgcn_readfirstlane(tid >> 6);  // 0..3

    const int b  = blk >> 8;              // batch
    const int oy = (blk >> 1) & 127;      // output row
    const int xh = blk & 1;               // row half
    const int ox = xh * 64 + lane;        // this lane's pixel

    float acc[COUT];
    #pragma unroll
    for (int o = 0; o < COUT; ++o) acc[o] = 0.f;

    dcn_pass<0, 5>(x, offs, mask, wt, b, oy, ox, wid, acc);
    dcn_pass<5, 4>(x, offs, mask, wt, b, oy, ox, wid, acc);

    // ---- cross-wave reduction, two 32-cout passes ----
    __shared__ float red[4][32][68];      // padded rows: 68*4B = 272B (16B-mult)
    const int o_loc = tid >> 3;           // 0..31
    const int px0   = (tid & 7) * 8;      // 0..56

    for (int h = 0; h < 2; ++h) {
        __syncthreads();
        #pragma unroll
        for (int j = 0; j < 32; ++j)
            red[wid][j][lane] = acc[h * 32 + j];
        __syncthreads();

        float s0 = 0.f, s1 = 0.f, s2 = 0.f, s3 = 0.f;
        float s4 = 0.f, s5 = 0.f, s6 = 0.f, s7 = 0.f;
        #pragma unroll
        for (int w4 = 0; w4 < 4; ++w4) {
            float4 a = *(const float4*)&red[w4][o_loc][px0];
            float4 c = *(const float4*)&red[w4][o_loc][px0 + 4];
            s0 += a.x; s1 += a.y; s2 += a.z; s3 += a.w;
            s4 += c.x; s5 += c.y; s6 += c.z; s7 += c.w;
        }
        const int o = h * 32 + o_loc;
        const float bv = bias[o];
        float* dst = out + (size_t)(((b * COUT + o) * HO + oy) * WO + xh * 64 + px0);
        *(float4*)dst       = make_float4(s0 + bv, s1 + bv, s2 + bv, s3 + bv);
        *(float4*)(dst + 4) = make_float4(s4 + bv, s5 + bv, s6 + bv, s7 + bv);
    }
}

extern "C" void kernel_launch(void* const* d_in, const int* in_sizes, int n_in,
                              void* d_out, int out_size, void* d_ws, size_t ws_size,
                              hipStream_t stream) {
    const float* x    = (const float*)d_in[0];
    const float* offs = (const float*)d_in[1];
    const float* mask = (const float*)d_in[2];
    const float* w    = (const float*)d_in[3];
    const float* bias = (const float*)d_in[4];
    float* out = (float*)d_out;
    float* wt  = (float*)d_ws;   // 576*64 floats

    hipLaunchKernelGGL(wt_kernel, dim3(144), dim3(256), 0, stream, w, wt);
    hipLaunchKernelGGL(dcn_main, dim3(BATCH * HO * 2), dim3(256), 0, stream,
                       x, offs, mask, wt, bias, out);
}

// Round 3
// 138.397 us; speedup vs baseline: 1.7862x; 1.7755x over previous
//
#include <hip/hip_runtime.h>

#define BATCH 4
#define CIN 64
#define H 128
#define W 128
#define COUT 64
#define KK 9
#define HO 128
#define WO 128

typedef short bf16x8 __attribute__((ext_vector_type(8)));
typedef float f32x4 __attribute__((ext_vector_type(4)));

__device__ __forceinline__ unsigned short f2bf(float f) {
    unsigned u = __builtin_bit_cast(unsigned, f);
    u += 0x7FFFu + ((u >> 16) & 1u);          // RNE
    return (unsigned short)(u >> 16);
}

// x[NCHW] -> xn[NHWC]  (pixel-major, 64 channels contiguous)
__global__ __launch_bounds__(256)
void nhwc_kernel(const float* __restrict__ x, float* __restrict__ xn) {
    const int blk = blockIdx.x;               // 1024 blocks
    const int tid = threadIdx.x;
    const int b = blk >> 8, y = (blk >> 1) & 127, xh = blk & 1;
    __shared__ float T[64][65];

    const int px = tid & 63, cq = tid >> 6;
    const float* src = x + (((size_t)b * 64) << 14) + y * 128 + xh * 64;
    #pragma unroll
    for (int j = 0; j < 16; ++j) {
        int c = cq * 16 + j;
        T[c][px] = src[((size_t)c << 14) + px];
    }
    __syncthreads();
    const int c2 = tid & 63, pq = tid >> 6;
    float* dst = xn + ((((size_t)b << 14) + y * 128 + xh * 64) << 6) + c2;
    #pragma unroll
    for (int j = 0; j < 16; ++j) {
        int p = pq * 16 + j;
        dst[(size_t)p << 6] = T[c2][p];
    }
}

// weight[COUT][CIN][3][3] -> wt2[o][r] bf16 with r = k*64 + c  (576 per o)
__global__ __launch_bounds__(256)
void wt2_kernel(const float* __restrict__ w, unsigned short* __restrict__ wt2) {
    int g = blockIdx.x * 256 + threadIdx.x;   // 0..36863
    int o = g / 576;
    int rem = g - o * 576;
    int k = rem >> 6, c = rem & 63;
    wt2[g] = f2bf(w[(o * 64 + c) * 9 + k]);
}

__global__ __launch_bounds__(256, 2)
void dcn_main(const float* __restrict__ xn, const float* __restrict__ offs,
              const float* __restrict__ mask, const unsigned short* __restrict__ wt2,
              const float* __restrict__ bias, float* __restrict__ out) {
    const int tid  = threadIdx.x;
    const int lane = tid & 63;
    const int wid  = tid >> 6;                 // 0..3
    const int blk  = blockIdx.x;               // 1024
    const int b  = blk >> 8;
    const int oy = (blk >> 1) & 127;
    const int xh = blk & 1;

    __shared__ unsigned short S[64 * 576];     // 72 KB, XOR-swizzled [px][r]

    // ---- W A-fragments in registers (per wave: couts wid*16..+15) ----
    bf16x8 afrag[18];
    {
        int o = wid * 16 + (lane & 15);
        const unsigned short* wp = wt2 + o * 576 + (lane >> 4) * 8;
        #pragma unroll
        for (int s = 0; s < 18; ++s)
            afrag[s] = *(const bf16x8*)(wp + s * 32);
    }

    // ---- Phase 1: coalesced gather into swizzled LDS ----
    const int base_bx = b << 14;
    for (int j = 0; j < 144; ++j) {
        int sp = wid * 144 + j;                // uniform per wave
        int k  = sp >> 6;                      // 0..8
        int px = sp & 63;
        int ox = xh * 64 + px;
        int kh = k / 3, kw = k - kh * 3;

        float offy = offs[((b * 18 + 2 * k    ) * 128 + oy) * 128 + ox];
        float offx = offs[((b * 18 + 2 * k + 1) * 128 + oy) * 128 + ox];
        float m    = mask[((b * 9  + k        ) * 128 + oy) * 128 + ox];

        float py  = (float)(oy - 1 + kh) + offy;
        float pxf = (float)(ox - 1 + kw) + offx;
        float fy = floorf(py), fx = floorf(pxf);
        float ly = py - fy, lx = pxf - fx;
        int y0 = (int)fy, x0 = (int)fx;
        int y1 = y0 + 1, x1 = x0 + 1;

        bool y0v = (y0 >= 0) & (y0 < H), y1v = (y1 >= 0) & (y1 < H);
        bool x0v = (x0 >= 0) & (x0 < W), x1v = (x1 >= 0) & (x1 < W);
        int y0c = min(max(y0, 0), H-1), y1c = min(max(y1, 0), H-1);
        int x0c = min(max(x0, 0), W-1), x1c = min(max(x1, 0), W-1);

        float w00 = (1.f - ly) * (1.f - lx) * m * ((y0v & x0v) ? 1.f : 0.f);
        float w01 = (1.f - ly) * lx         * m * ((y0v & x1v) ? 1.f : 0.f);
        float w10 = ly         * (1.f - lx) * m * ((y1v & x0v) ? 1.f : 0.f);
        float w11 = ly         * lx         * m * ((y1v & x1v) ? 1.f : 0.f);

        const float* p00 = xn + (((size_t)(base_bx + y0c * 128 + x0c)) << 6) + lane;
        int d1 = (x1c - x0c) << 6;             // 0 or 64
        int d2 = (y1c - y0c) << 13;            // 0 or 8192
        float v00 = p00[0];
        float v01 = p00[d1];
        float v10 = p00[d2];
        float v11 = p00[d1 + d2];

        float v = fmaf(w00, v00, fmaf(w01, v01, fmaf(w10, v10, w11 * v11)));

        int r = (k << 6) + lane;               // K-row = k*64 + c
        int byteoff = px * 1152 + ((r * 2) ^ ((px & 7) << 4));
        *(unsigned short*)((char*)S + byteoff) = f2bf(v);
    }
    __syncthreads();

    // ---- Phase 2: MFMA sweep, K = 576 (18 steps of 32) ----
    f32x4 acc[4] = {};
    #pragma unroll
    for (int s = 0; s < 18; ++s) {
        #pragma unroll
        for (int t = 0; t < 4; ++t) {
            int pxr   = t * 16 + (lane & 15);
            int relem = s * 32 + (lane >> 4) * 8;
            int byteoff = pxr * 1152 + ((relem * 2) ^ ((pxr & 7) << 4));
            bf16x8 bfrag = *(const bf16x8*)((const char*)S + byteoff);
            acc[t] = __builtin_amdgcn_mfma_f32_16x16x32_bf16(afrag[s], bfrag, acc[t], 0, 0, 0);
        }
    }

    // ---- Epilogue ----
    const int q0 = (lane >> 4) * 4;
    float bv[4];
    #pragma unroll
    for (int q = 0; q < 4; ++q) bv[q] = bias[wid * 16 + q0 + q];
    #pragma unroll
    for (int t = 0; t < 4; ++t) {
        #pragma unroll
        for (int q = 0; q < 4; ++q) {
            int o  = wid * 16 + q0 + q;
            int ox = xh * 64 + t * 16 + (lane & 15);
            out[(((size_t)(b * 64 + o)) * 128 + oy) * 128 + ox] = acc[t][q] + bv[q];
        }
    }
}

extern "C" void kernel_launch(void* const* d_in, const int* in_sizes, int n_in,
                              void* d_out, int out_size, void* d_ws, size_t ws_size,
                              hipStream_t stream) {
    const float* x    = (const float*)d_in[0];
    const float* offs = (const float*)d_in[1];
    const float* mask = (const float*)d_in[2];
    const float* w    = (const float*)d_in[3];
    const float* bias = (const float*)d_in[4];
    float* out = (float*)d_out;

    float*          xn  = (float*)d_ws;                          // 16 MB
    unsigned short* wt2 = (unsigned short*)((char*)d_ws + (16u << 20));  // 72 KB

    hipLaunchKernelGGL(nhwc_kernel, dim3(1024), dim3(256), 0, stream, x, xn);
    hipLaunchKernelGGL(wt2_kernel, dim3(144), dim3(256), 0, stream, w, wt2);
    hipLaunchKernelGGL(dcn_main, dim3(1024), dim3(256), 0, stream,
                       xn, offs, mask, wt2, bias, out);
}

// Round 4
// 87.193 us; speedup vs baseline: 2.8352x; 1.5872x over previous
//
#include <hip/hip_runtime.h>

#define BATCH 4
#define CIN 64
#define H 128
#define W 128
#define COUT 64
#define KK 9
#define HO 128
#define WO 128

typedef short bf16x8 __attribute__((ext_vector_type(8)));
typedef float f32x4 __attribute__((ext_vector_type(4)));

__device__ __forceinline__ unsigned short f2bf(float f) {
    unsigned u = __builtin_bit_cast(unsigned, f);
    u += 0x7FFFu + ((u >> 16) & 1u);          // RNE
    return (unsigned short)(u >> 16);
}
__device__ __forceinline__ float bf2f(unsigned short h) {
    return __builtin_bit_cast(float, (unsigned)h << 16);
}

// Fused prep:
//  blocks 0..1023   : (b,oy,xh) NCHW->NHWC bf16 transpose + 576 sample descriptors
//  blocks 1024..1167: weight transpose  w[COUT][CIN][3][3] -> wt2[o][k*64+c] bf16
__global__ __launch_bounds__(256)
void prep(const float* __restrict__ x, const float* __restrict__ offs,
          const float* __restrict__ mask, const float* __restrict__ w,
          unsigned short* __restrict__ xn, unsigned short* __restrict__ wt2,
          int* __restrict__ di, float* __restrict__ dw) {
    const int blk = blockIdx.x;
    const int tid = threadIdx.x;

    if (blk >= 1024) {
        int g = (blk - 1024) * 256 + tid;     // 0..36863
        int o = g / 576;
        int rem = g - o * 576;
        int k = rem >> 6, c = rem & 63;
        wt2[g] = f2bf(w[(o * 64 + c) * 9 + k]);
        return;
    }

    const int b = blk >> 8, oy = (blk >> 1) & 127, xh = blk & 1;

    // ---- NHWC bf16 transpose for this 64-px row-half ----
    __shared__ float T[64][65];
    {
        const int px = tid & 63, cq = tid >> 6;
        const float* src = x + (((size_t)b * 64) << 14) + oy * 128 + xh * 64;
        #pragma unroll
        for (int j = 0; j < 16; ++j) {
            int c = cq * 16 + j;
            T[c][px] = src[((size_t)c << 14) + px];
        }
        __syncthreads();
        const int c2 = tid & 63, pq = tid >> 6;
        unsigned short* dst = xn + ((((size_t)b << 14) + oy * 128 + xh * 64) << 6) + c2;
        #pragma unroll
        for (int j = 0; j < 16; ++j) {
            int p = pq * 16 + j;
            dst[(size_t)p << 6] = f2bf(T[c2][p]);
        }
    }

    // ---- descriptors: one lane per sample point ----
    const int gbase = blk * 576;
    #pragma unroll
    for (int i = 0; i < 3; ++i) {
        int s = i * 256 + tid;
        if (s < 576) {
            int k = s >> 6, spx = s & 63;
            int ox = xh * 64 + spx;
            int kh = k / 3, kw = k - kh * 3;

            float offy = offs[((b * 18 + 2 * k    ) * 128 + oy) * 128 + ox];
            float offx = offs[((b * 18 + 2 * k + 1) * 128 + oy) * 128 + ox];
            float m    = mask[((b * 9  + k        ) * 128 + oy) * 128 + ox];

            float py  = (float)(oy - 1 + kh) + offy;
            float pxf = (float)(ox - 1 + kw) + offx;
            float fy = floorf(py), fx = floorf(pxf);
            float ly = py - fy, lx = pxf - fx;
            int y0 = (int)fy, x0 = (int)fx;
            int y1 = y0 + 1, x1 = x0 + 1;

            bool y0v = (y0 >= 0) & (y0 < H), y1v = (y1 >= 0) & (y1 < H);
            bool x0v = (x0 >= 0) & (x0 < W), x1v = (x1 >= 0) & (x1 < W);
            int y0c = min(max(y0, 0), H-1), y1c = min(max(y1, 0), H-1);
            int x0c = min(max(x0, 0), W-1), x1c = min(max(x1, 0), W-1);

            int p00 = (b << 14) + y0c * 128 + x0c;            // fits 16 bits
            int dx = x1c - x0c, dy = y1c - y0c;
            di[gbase + s] = p00 | (dx << 16) | (dy << 17);

            f32x4 wv;
            wv[0] = (1.f - ly) * (1.f - lx) * m * ((y0v & x0v) ? 1.f : 0.f);
            wv[1] = (1.f - ly) * lx         * m * ((y0v & x1v) ? 1.f : 0.f);
            wv[2] = ly         * (1.f - lx) * m * ((y1v & x0v) ? 1.f : 0.f);
            wv[3] = ly         * lx         * m * ((y1v & x1v) ? 1.f : 0.f);
            *(f32x4*)(dw + (size_t)(gbase + s) * 4) = wv;
        }
    }
}

__global__ __launch_bounds__(256, 2)
void dcn_main(const unsigned short* __restrict__ xn, const unsigned short* __restrict__ wt2,
              const int* __restrict__ di, const float* __restrict__ dw,
              const float* __restrict__ bias, float* __restrict__ out) {
    const int tid  = threadIdx.x;
    const int lane = tid & 63;
    const int wid  = __builtin_amdgcn_readfirstlane(tid >> 6);
    const int blk  = blockIdx.x;
    const int b  = blk >> 8;
    const int oy = (blk >> 1) & 127;
    const int xh = blk & 1;

    __shared__ __align__(16) unsigned short S[64 * 576];   // 72 KB swizzled [px][r]

    // ---- W A-fragments (per wave: couts wid*16..+15), K-order r=k*64+c ----
    bf16x8 afrag[18];
    {
        int o = wid * 16 + (lane & 15);
        const unsigned short* wp = wt2 + o * 576 + (lane >> 4) * 8;
        #pragma unroll
        for (int s = 0; s < 18; ++s)
            afrag[s] = *(const bf16x8*)(wp + s * 32);
    }

    // ---- gather: descriptor via scalar loads, coalesced bf16 corners ----
    const int gbase0 = blk * 576 + wid * 144;
    const int lane2  = lane * 2;
    #pragma unroll 4
    for (int j = 0; j < 144; ++j) {
        int sidx = __builtin_amdgcn_readfirstlane(gbase0 + j);
        int d = di[sidx];                                   // s_load_dword
        f32x4 wv = *(const f32x4*)(dw + (size_t)sidx * 4);  // s_load_dwordx4

        int p00 = d & 0xFFFF;
        int o01 = ((d >> 16) & 1) << 6;     // element offsets in xn
        int o10 = ((d >> 17) & 1) << 13;

        const unsigned short* pb = xn + ((size_t)p00 << 6);
        float v00 = bf2f(pb[lane]);
        float v01 = bf2f(pb[o01 + lane]);
        float v10 = bf2f(pb[o10 + lane]);
        float v11 = bf2f(pb[o01 + o10 + lane]);

        float v = fmaf(wv[0], v00, fmaf(wv[1], v01, fmaf(wv[2], v10, wv[3] * v11)));

        int sp = wid * 144 + j;             // uniform
        int px = sp & 63, k = sp >> 6;
        int sbase = px * 1152 + k * 128;
        int sxor  = (px & 7) << 4;
        *(unsigned short*)((char*)S + sbase + (lane2 ^ sxor)) = f2bf(v);
    }
    __syncthreads();

    // ---- MFMA sweep, K = 576 (18 steps of 32) ----
    f32x4 acc[4] = {};
    #pragma unroll
    for (int s = 0; s < 18; ++s) {
        #pragma unroll
        for (int t = 0; t < 4; ++t) {
            int pxr   = t * 16 + (lane & 15);
            int relem = s * 32 + (lane >> 4) * 8;
            int byteoff = pxr * 1152 + ((relem * 2) ^ ((pxr & 7) << 4));
            bf16x8 bfrag = *(const bf16x8*)((const char*)S + byteoff);
            acc[t] = __builtin_amdgcn_mfma_f32_16x16x32_bf16(afrag[s], bfrag, acc[t], 0, 0, 0);
        }
    }

    // ---- Epilogue ----
    const int q0 = (lane >> 4) * 4;
    float bv[4];
    #pragma unroll
    for (int q = 0; q < 4; ++q) bv[q] = bias[wid * 16 + q0 + q];
    #pragma unroll
    for (int t = 0; t < 4; ++t) {
        #pragma unroll
        for (int q = 0; q < 4; ++q) {
            int o  = wid * 16 + q0 + q;
            int ox = xh * 64 + t * 16 + (lane & 15);
            out[(((size_t)(b * 64 + o)) * 128 + oy) * 128 + ox] = acc[t][q] + bv[q];
        }
    }
}

extern "C" void kernel_launch(void* const* d_in, const int* in_sizes, int n_in,
                              void* d_out, int out_size, void* d_ws, size_t ws_size,
                              hipStream_t stream) {
    const float* x    = (const float*)d_in[0];
    const float* offs = (const float*)d_in[1];
    const float* mask = (const float*)d_in[2];
    const float* w    = (const float*)d_in[3];
    const float* bias = (const float*)d_in[4];
    float* out = (float*)d_out;

    // workspace layout
    char* ws = (char*)d_ws;
    unsigned short* xn  = (unsigned short*)(ws);                   //  8 MB  (bf16 NHWC)
    unsigned short* wt2 = (unsigned short*)(ws + (8u  << 20));     // 72 KB
    int*            di  = (int*)           (ws + (9u  << 20));     // ~2.4 MB
    float*          dw  = (float*)         (ws + (12u << 20));     // ~9.5 MB
    // total ~21.5 MB

    hipLaunchKernelGGL(prep, dim3(1168), dim3(256), 0, stream,
                       x, offs, mask, w, xn, wt2, di, dw);
    hipLaunchKernelGGL(dcn_main, dim3(1024), dim3(256), 0, stream,
                       xn, wt2, di, dw, bias, out);
}

// Round 5
// 79.463 us; speedup vs baseline: 3.1110x; 1.0973x over previous
//
#include <hip/hip_runtime.h>

#define BATCH 4
#define CIN 64
#define H 128
#define W 128
#define COUT 64
#define KK 9
#define HO 128
#define WO 128

typedef short bf16x8 __attribute__((ext_vector_type(8)));
typedef float f32x4 __attribute__((ext_vector_type(4)));

__device__ __forceinline__ unsigned short f2bf(float f) {
    unsigned u = __builtin_bit_cast(unsigned, f);
    u += 0x7FFFu + ((u >> 16) & 1u);          // RNE
    return (unsigned short)(u >> 16);
}
__device__ __forceinline__ float bf2f(unsigned short h) {
    return __builtin_bit_cast(float, (unsigned)h << 16);
}

// Fused prep:
//  blocks 0..1023   : (b,oy,xh) NCHW->NHWC bf16 transpose + 576 sample descriptors
//  blocks 1024..1167: weight transpose  w[COUT][CIN][3][3] -> wt2[o][k*64+c] bf16
__global__ __launch_bounds__(256)
void prep(const float* __restrict__ x, const float* __restrict__ offs,
          const float* __restrict__ mask, const float* __restrict__ w,
          unsigned short* __restrict__ xn, unsigned short* __restrict__ wt2,
          int* __restrict__ di, float* __restrict__ dw) {
    const int blk = blockIdx.x;
    const int tid = threadIdx.x;

    if (blk >= 1024) {
        int g = (blk - 1024) * 256 + tid;     // 0..36863
        int o = g / 576;
        int rem = g - o * 576;
        int k = rem >> 6, c = rem & 63;
        wt2[g] = f2bf(w[(o * 64 + c) * 9 + k]);
        return;
    }

    const int b = blk >> 8, oy = (blk >> 1) & 127, xh = blk & 1;

    // ---- NHWC bf16 transpose for this 64-px row-half ----
    __shared__ float T[64][65];
    {
        const int px = tid & 63, cq = tid >> 6;
        const float* src = x + (((size_t)b * 64) << 14) + oy * 128 + xh * 64;
        #pragma unroll
        for (int j = 0; j < 16; ++j) {
            int c = cq * 16 + j;
            T[c][px] = src[((size_t)c << 14) + px];
        }
        __syncthreads();
        const int c2 = tid & 63, pq = tid >> 6;
        unsigned short* dst = xn + ((((size_t)b << 14) + oy * 128 + xh * 64) << 6) + c2;
        #pragma unroll
        for (int j = 0; j < 16; ++j) {
            int p = pq * 16 + j;
            dst[(size_t)p << 6] = f2bf(T[c2][p]);
        }
    }

    // ---- descriptors: one lane per sample point ----
    const int gbase = blk * 576;
    #pragma unroll
    for (int i = 0; i < 3; ++i) {
        int s = i * 256 + tid;
        if (s < 576) {
            int k = s >> 6, spx = s & 63;
            int ox = xh * 64 + spx;
            int kh = k / 3, kw = k - kh * 3;

            float offy = offs[((b * 18 + 2 * k    ) * 128 + oy) * 128 + ox];
            float offx = offs[((b * 18 + 2 * k + 1) * 128 + oy) * 128 + ox];
            float m    = mask[((b * 9  + k        ) * 128 + oy) * 128 + ox];

            float py  = (float)(oy - 1 + kh) + offy;
            float pxf = (float)(ox - 1 + kw) + offx;
            float fy = floorf(py), fx = floorf(pxf);
            float ly = py - fy, lx = pxf - fx;
            int y0 = (int)fy, x0 = (int)fx;
            int y1 = y0 + 1, x1 = x0 + 1;

            bool y0v = (y0 >= 0) & (y0 < H), y1v = (y1 >= 0) & (y1 < H);
            bool x0v = (x0 >= 0) & (x0 < W), x1v = (x1 >= 0) & (x1 < W);
            int y0c = min(max(y0, 0), H-1), y1c = min(max(y1, 0), H-1);
            int x0c = min(max(x0, 0), W-1), x1c = min(max(x1, 0), W-1);

            int p00 = (b << 14) + y0c * 128 + x0c;            // fits 16 bits
            int dx = x1c - x0c, dy = y1c - y0c;
            di[gbase + s] = p00 | (dx << 16) | (dy << 17);

            f32x4 wv;
            wv[0] = (1.f - ly) * (1.f - lx) * m * ((y0v & x0v) ? 1.f : 0.f);
            wv[1] = (1.f - ly) * lx         * m * ((y0v & x1v) ? 1.f : 0.f);
            wv[2] = ly         * (1.f - lx) * m * ((y1v & x0v) ? 1.f : 0.f);
            wv[3] = ly         * lx         * m * ((y1v & x1v) ? 1.f : 0.f);
            *(f32x4*)(dw + (size_t)(gbase + s) * 4) = wv;
        }
    }
}

__global__ __launch_bounds__(256, 4)
void dcn_main(const unsigned short* __restrict__ xn, const unsigned short* __restrict__ wt2,
              const int* __restrict__ di, const float* __restrict__ dw,
              const float* __restrict__ bias, float* __restrict__ out) {
    const int tid  = threadIdx.x;
    const int lane = tid & 63;
    const int wid  = tid >> 6;
    const int blk  = blockIdx.x;
    const int b  = blk >> 8;
    const int oy = (blk >> 1) & 127;
    const int xh = blk & 1;

    __shared__ __align__(16) unsigned short S[32 * 576];   // 36 KB swizzled [pxl][r]

    const int lane2 = lane * 2;

    #pragma unroll 1
    for (int p = 0; p < 2; ++p) {
        if (p) __syncthreads();            // previous phase's MFMA reads done

        const int sbase = blk * 576 + p * 32;

        // ---- gather: depth-1 pipelined descriptor loads (vmcnt only) ----
        int4 din; f32x4 dwn0, dwn1, dwn2, dwn3;
        {
            int sp0 = wid * 72;
            int sidx0 = sbase + (sp0 >> 5) * 64 + (sp0 & 31);
            din = *(const int4*)(di + sidx0);
            const f32x4* q = (const f32x4*)(dw + (size_t)sidx0 * 4);
            dwn0 = q[0]; dwn1 = q[1]; dwn2 = q[2]; dwn3 = q[3];
        }
        #pragma unroll 2
        for (int g = 0; g < 18; ++g) {
            int4 dic = din;
            f32x4 wv0 = dwn0, wv1 = dwn1, wv2 = dwn2, wv3 = dwn3;
            if (g < 17) {
                int spn = wid * 72 + (g + 1) * 4;
                int sidxn = sbase + (spn >> 5) * 64 + (spn & 31);
                din = *(const int4*)(di + sidxn);
                const f32x4* q = (const f32x4*)(dw + (size_t)sidxn * 4);
                dwn0 = q[0]; dwn1 = q[1]; dwn2 = q[2]; dwn3 = q[3];
            }
            int dd[4] = {dic.x, dic.y, dic.z, dic.w};
            unsigned short c00[4], c01[4], c10[4], c11[4];
            #pragma unroll
            for (int i = 0; i < 4; ++i) {
                int d = dd[i];
                const unsigned short* pb = xn + ((size_t)(d & 0xFFFF) << 6);
                int o01 = ((d >> 16) & 1) << 6;
                int o10 = ((d >> 17) & 1) << 13;
                c00[i] = pb[lane];
                c01[i] = pb[o01 + lane];
                c10[i] = pb[o10 + lane];
                c11[i] = pb[o01 + o10 + lane];
            }
            int sp = wid * 72 + g * 4;
            int k = sp >> 5, pxl0 = sp & 31;
            f32x4 wv[4] = {wv0, wv1, wv2, wv3};
            #pragma unroll
            for (int i = 0; i < 4; ++i) {
                float v = fmaf(wv[i][0], bf2f(c00[i]),
                          fmaf(wv[i][1], bf2f(c01[i]),
                          fmaf(wv[i][2], bf2f(c10[i]), wv[i][3] * bf2f(c11[i]))));
                int pxl = pxl0 + i;
                int sb = pxl * 1152 + k * 128;
                *(unsigned short*)((char*)S + sb + (lane2 ^ ((pxl & 7) << 4))) = f2bf(v);
            }
        }
        __syncthreads();

        // ---- A fragments (per wave: couts wid*16..+15), loaded from L2-hot wt2 ----
        bf16x8 afrag[18];
        {
            int o = wid * 16 + (lane & 15);
            const unsigned short* wp = wt2 + o * 576 + (lane >> 4) * 8;
            #pragma unroll
            for (int s = 0; s < 18; ++s)
                afrag[s] = *(const bf16x8*)(wp + s * 32);
        }

        // ---- MFMA sweep, K = 576, 2 pixel-tiles this phase ----
        f32x4 acc[2] = {};
        #pragma unroll
        for (int s = 0; s < 18; ++s) {
            #pragma unroll
            for (int tt = 0; tt < 2; ++tt) {
                int pxr   = tt * 16 + (lane & 15);
                int relem = s * 32 + (lane >> 4) * 8;
                int byteoff = pxr * 1152 + ((relem * 2) ^ ((pxr & 7) << 4));
                bf16x8 bfrag = *(const bf16x8*)((const char*)S + byteoff);
                acc[tt] = __builtin_amdgcn_mfma_f32_16x16x32_bf16(afrag[s], bfrag, acc[tt], 0, 0, 0);
            }
        }

        // ---- epilogue for this phase's 32 pixels ----
        const int q0 = (lane >> 4) * 4;
        #pragma unroll
        for (int tt = 0; tt < 2; ++tt) {
            #pragma unroll
            for (int q = 0; q < 4; ++q) {
                int o  = wid * 16 + q0 + q;
                int ox = xh * 64 + p * 32 + tt * 16 + (lane & 15);
                out[(((size_t)(b * 64 + o)) * 128 + oy) * 128 + ox] = acc[tt][q] + bias[o];
            }
        }
    }
}

extern "C" void kernel_launch(void* const* d_in, const int* in_sizes, int n_in,
                              void* d_out, int out_size, void* d_ws, size_t ws_size,
                              hipStream_t stream) {
    const float* x    = (const float*)d_in[0];
    const float* offs = (const float*)d_in[1];
    const float* mask = (const float*)d_in[2];
    const float* w    = (const float*)d_in[3];
    const float* bias = (const float*)d_in[4];
    float* out = (float*)d_out;

    // workspace layout
    char* ws = (char*)d_ws;
    unsigned short* xn  = (unsigned short*)(ws);                   //  8 MB  (bf16 NHWC)
    unsigned short* wt2 = (unsigned short*)(ws + (8u  << 20));     // 72 KB
    int*            di  = (int*)           (ws + (9u  << 20));     // ~2.4 MB
    float*          dw  = (float*)         (ws + (12u << 20));     // ~9.5 MB

    hipLaunchKernelGGL(prep, dim3(1168), dim3(256), 0, stream,
                       x, offs, mask, w, xn, wt2, di, dw);
    hipLaunchKernelGGL(dcn_main, dim3(1024), dim3(256), 0, stream,
                       xn, wt2, di, dw, bias, out);
}

// Round 6
// 61.195 us; speedup vs baseline: 4.0397x; 1.2985x over previous
//
#include <hip/hip_runtime.h>

#define BATCH 4
#define CIN 64
#define H 128
#define W 128
#define COUT 64
#define KK 9
#define HO 128
#define WO 128

typedef short bf16x8 __attribute__((ext_vector_type(8)));
typedef float f32x4 __attribute__((ext_vector_type(4)));

__device__ __forceinline__ unsigned short f2bf(float f) {
    unsigned u = __builtin_bit_cast(unsigned, f);
    u += 0x7FFFu + ((u >> 16) & 1u);          // RNE
    return (unsigned short)(u >> 16);
}
__device__ __forceinline__ float bflo(unsigned u) {   // low bf16 of dword
    return __builtin_bit_cast(float, u << 16);
}
__device__ __forceinline__ float bfhi(unsigned u) {   // high bf16 of dword
    return __builtin_bit_cast(float, u & 0xFFFF0000u);
}

// Fused prep:
//  blocks 0..1023   : (b,oy,xh) NCHW->NHWC bf16 transpose + 576 sample descriptors
//  blocks 1024..1167: weight transpose  w[COUT][CIN][3][3] -> wt2[o][k*64+c] bf16
__global__ __launch_bounds__(256)
void prep(const float* __restrict__ x, const float* __restrict__ offs,
          const float* __restrict__ mask, const float* __restrict__ w,
          unsigned short* __restrict__ xn, unsigned short* __restrict__ wt2,
          int* __restrict__ di, float* __restrict__ dw) {
    const int blk = blockIdx.x;
    const int tid = threadIdx.x;

    if (blk >= 1024) {
        int g = (blk - 1024) * 256 + tid;     // 0..36863
        int o = g / 576;
        int rem = g - o * 576;
        int k = rem >> 6, c = rem & 63;
        wt2[g] = f2bf(w[(o * 64 + c) * 9 + k]);
        return;
    }

    const int b = blk >> 8, oy = (blk >> 1) & 127, xh = blk & 1;

    // ---- NHWC bf16 transpose for this 64-px row-half ----
    __shared__ float T[64][65];
    {
        const int px = tid & 63, cq = tid >> 6;
        const float* src = x + (((size_t)b * 64) << 14) + oy * 128 + xh * 64;
        #pragma unroll
        for (int j = 0; j < 16; ++j) {
            int c = cq * 16 + j;
            T[c][px] = src[((size_t)c << 14) + px];
        }
        __syncthreads();
        const int c2 = tid & 63, pq = tid >> 6;
        unsigned short* dst = xn + ((((size_t)b << 14) + oy * 128 + xh * 64) << 6) + c2;
        #pragma unroll
        for (int j = 0; j < 16; ++j) {
            int p = pq * 16 + j;
            dst[(size_t)p << 6] = f2bf(T[c2][p]);
        }
    }

    // ---- descriptors: one lane per sample point ----
    const int gbase = blk * 576;
    #pragma unroll
    for (int i = 0; i < 3; ++i) {
        int s = i * 256 + tid;
        if (s < 576) {
            int k = s >> 6, spx = s & 63;
            int ox = xh * 64 + spx;
            int kh = k / 3, kw = k - kh * 3;

            float offy = offs[((b * 18 + 2 * k    ) * 128 + oy) * 128 + ox];
            float offx = offs[((b * 18 + 2 * k + 1) * 128 + oy) * 128 + ox];
            float m    = mask[((b * 9  + k        ) * 128 + oy) * 128 + ox];

            float py  = (float)(oy - 1 + kh) + offy;
            float pxf = (float)(ox - 1 + kw) + offx;
            float fy = floorf(py), fx = floorf(pxf);
            float ly = py - fy, lx = pxf - fx;
            int y0 = (int)fy, x0 = (int)fx;
            int y1 = y0 + 1, x1 = x0 + 1;

            bool y0v = (y0 >= 0) & (y0 < H), y1v = (y1 >= 0) & (y1 < H);
            bool x0v = (x0 >= 0) & (x0 < W), x1v = (x1 >= 0) & (x1 < W);
            int y0c = min(max(y0, 0), H-1), y1c = min(max(y1, 0), H-1);
            int x0c = min(max(x0, 0), W-1), x1c = min(max(x1, 0), W-1);

            int p00 = (b << 14) + y0c * 128 + x0c;            // fits 16 bits
            int dx = x1c - x0c, dy = y1c - y0c;
            di[gbase + s] = p00 | (dx << 16) | (dy << 17);

            f32x4 wv;
            wv[0] = (1.f - ly) * (1.f - lx) * m * ((y0v & x0v) ? 1.f : 0.f);
            wv[1] = (1.f - ly) * lx         * m * ((y0v & x1v) ? 1.f : 0.f);
            wv[2] = ly         * (1.f - lx) * m * ((y1v & x0v) ? 1.f : 0.f);
            wv[3] = ly         * lx         * m * ((y1v & x1v) ? 1.f : 0.f);
            *(f32x4*)(dw + (size_t)(gbase + s) * 4) = wv;
        }
    }
}

__global__ __launch_bounds__(256, 4)
void dcn_main(const unsigned short* __restrict__ xn, const unsigned short* __restrict__ wt2,
              const int* __restrict__ di, const float* __restrict__ dw,
              const float* __restrict__ bias, float* __restrict__ out) {
    const int tid  = threadIdx.x;
    const int lane = tid & 63;
    const int wid  = tid >> 6;
    const int blk  = blockIdx.x;
    const int b  = blk >> 8;
    const int oy = (blk >> 1) & 127;
    const int xh = blk & 1;
    const int hf = lane >> 5;           // sample half (0: sample 2p, 1: sample 2p+1)
    const int cl = lane & 31;           // channel-dword index (channels 2cl, 2cl+1)

    __shared__ __align__(16) unsigned short S[32 * 576];   // 36 KB swizzled [pxl][r]
    const unsigned* xw = (const unsigned*)xn;              // dword view: [px][32]

    // per-wave cout slice + bias (constant across both phases)
    const int q0 = (lane >> 4) * 4;
    float bv[4];
    #pragma unroll
    for (int q = 0; q < 4; ++q) bv[q] = bias[wid * 16 + q0 + q];

    const int spb = wid * 72;

    #pragma unroll 1
    for (int p = 0; p < 2; ++p) {
        if (p) __syncthreads();
        const int sbase = blk * 576 + p * 32;

        // ---- gather: paired samples, parity-double-buffered descriptors ----
        int4  dinA, dinB;
        f32x4 wA0, wA1, wA2, wA3, wB0, wB1, wB2, wB3;

        {   // slot A <- group 0
            int sp = spb;
            int si = sbase + ((sp >> 5) << 6) + (sp & 31);
            dinA = *(const int4*)(di + si);
            const f32x4* q_ = (const f32x4*)(dw + (size_t)si * 4);
            wA0 = q_[0]; wA1 = q_[1]; wA2 = q_[2]; wA3 = q_[3];
        }

        #define PROCESS(G, DIN, W0, W1, W2, W3)                                     \
        {                                                                           \
            int sp_  = spb + (G) * 4;                                               \
            int k_   = sp_ >> 5;                                                    \
            int pxl0 = sp_ & 31;                                                    \
            unsigned u_[2][4];                                                      \
            float    c_[2][4];                                                      \
            _Pragma("unroll")                                                       \
            for (int pr = 0; pr < 2; ++pr) {                                        \
                int d0 = pr ? DIN.z : DIN.x;                                        \
                int d1 = pr ? DIN.w : DIN.y;                                        \
                int d  = hf ? d1 : d0;                                              \
                unsigned base = ((unsigned)(d & 0xFFFF) << 5) + (unsigned)cl;       \
                unsigned o01  = ((unsigned)(d >> 16) & 1u) << 5;                    \
                unsigned o10  = ((unsigned)(d >> 17) & 1u) << 12;                   \
                u_[pr][0] = xw[base];                                               \
                u_[pr][1] = xw[base + o01];                                         \
                u_[pr][2] = xw[base + o10];                                         \
                u_[pr][3] = xw[base + o01 + o10];                                   \
                f32x4 wsA = pr ? W2 : W0;                                           \
                f32x4 wsB = pr ? W3 : W1;                                           \
                c_[pr][0] = hf ? wsB[0] : wsA[0];                                   \
                c_[pr][1] = hf ? wsB[1] : wsA[1];                                   \
                c_[pr][2] = hf ? wsB[2] : wsA[2];                                   \
                c_[pr][3] = hf ? wsB[3] : wsA[3];                                   \
            }                                                                       \
            _Pragma("unroll")                                                       \
            for (int pr = 0; pr < 2; ++pr) {                                        \
                float lo = fmaf(c_[pr][0], bflo(u_[pr][0]),                         \
                           fmaf(c_[pr][1], bflo(u_[pr][1]),                         \
                           fmaf(c_[pr][2], bflo(u_[pr][2]),                         \
                                c_[pr][3] * bflo(u_[pr][3]))));                     \
                float hi = fmaf(c_[pr][0], bfhi(u_[pr][0]),                         \
                           fmaf(c_[pr][1], bfhi(u_[pr][1]),                         \
                           fmaf(c_[pr][2], bfhi(u_[pr][2]),                         \
                                c_[pr][3] * bfhi(u_[pr][3]))));                     \
                unsigned pk_;                                                       \
                asm("v_cvt_pk_bf16_f32 %0, %1, %2" : "=v"(pk_) : "v"(lo), "v"(hi)); \
                int pxl = pxl0 + 2 * pr + hf;                                       \
                int sb  = pxl * 1152 + k_ * 128 + ((cl * 4) ^ ((pxl & 7) << 4));    \
                *(unsigned*)((char*)S + sb) = pk_;                                  \
            }                                                                       \
        }

        #pragma unroll 1
        for (int gg = 0; gg < 9; ++gg) {
            {   // slot B <- group 2gg+1
                int sp = spb + (2 * gg + 1) * 4;
                int si = sbase + ((sp >> 5) << 6) + (sp & 31);
                dinB = *(const int4*)(di + si);
                const f32x4* q_ = (const f32x4*)(dw + (size_t)si * 4);
                wB0 = q_[0]; wB1 = q_[1]; wB2 = q_[2]; wB3 = q_[3];
            }
            PROCESS(2 * gg, dinA, wA0, wA1, wA2, wA3)
            if (gg < 8) {   // slot A <- group 2gg+2
                int sp = spb + (2 * gg + 2) * 4;
                int si = sbase + ((sp >> 5) << 6) + (sp & 31);
                dinA = *(const int4*)(di + si);
                const f32x4* q_ = (const f32x4*)(dw + (size_t)si * 4);
                wA0 = q_[0]; wA1 = q_[1]; wA2 = q_[2]; wA3 = q_[3];
            }
            PROCESS(2 * gg + 1, dinB, wB0, wB1, wB2, wB3)
        }
        #undef PROCESS
        __syncthreads();

        // ---- MFMA sweep, K = 576, afrag depth-1 prefetched from L2-hot wt2 ----
        f32x4 acc0 = {}, acc1 = {};
        {
            int o = wid * 16 + (lane & 15);
            const unsigned short* wp = wt2 + o * 576 + (lane >> 4) * 8;
            const int pxr0 = lane & 15;
            const int rb   = (lane >> 4) * 16;            // byte col base
            const int swz0 = (pxr0 & 7) << 4;
            const int bo0base = pxr0 * 1152;
            const int bo1base = (pxr0 + 16) * 1152;

            bf16x8 afA = *(const bf16x8*)(wp);
            bf16x8 afB;
            #pragma unroll 1
            for (int ss = 0; ss < 9; ++ss) {
                afB = *(const bf16x8*)(wp + (2 * ss + 1) * 32);
                {
                    int colx = (2 * ss * 64 + rb) ^ swz0;
                    bf16x8 b0 = *(const bf16x8*)((const char*)S + bo0base + colx);
                    bf16x8 b1 = *(const bf16x8*)((const char*)S + bo1base + colx);
                    acc0 = __builtin_amdgcn_mfma_f32_16x16x32_bf16(afA, b0, acc0, 0, 0, 0);
                    acc1 = __builtin_amdgcn_mfma_f32_16x16x32_bf16(afA, b1, acc1, 0, 0, 0);
                }
                if (ss < 8) afA = *(const bf16x8*)(wp + (2 * ss + 2) * 32);
                {
                    int colx = ((2 * ss + 1) * 64 + rb) ^ swz0;
                    bf16x8 b0 = *(const bf16x8*)((const char*)S + bo0base + colx);
                    bf16x8 b1 = *(const bf16x8*)((const char*)S + bo1base + colx);
                    acc0 = __builtin_amdgcn_mfma_f32_16x16x32_bf16(afB, b0, acc0, 0, 0, 0);
                    acc1 = __builtin_amdgcn_mfma_f32_16x16x32_bf16(afB, b1, acc1, 0, 0, 0);
                }
            }
        }

        // ---- epilogue for this phase's 32 pixels ----
        #pragma unroll
        for (int q = 0; q < 4; ++q) {
            int o  = wid * 16 + q0 + q;
            int oxb = xh * 64 + p * 32 + (lane & 15);
            float* dst = out + (((size_t)(b * 64 + o)) * 128 + oy) * 128 + oxb;
            dst[0]  = acc0[q] + bv[q];
            dst[16] = acc1[q] + bv[q];
        }
    }
}

extern "C" void kernel_launch(void* const* d_in, const int* in_sizes, int n_in,
                              void* d_out, int out_size, void* d_ws, size_t ws_size,
                              hipStream_t stream) {
    const float* x    = (const float*)d_in[0];
    const float* offs = (const float*)d_in[1];
    const float* mask = (const float*)d_in[2];
    const float* w    = (const float*)d_in[3];
    const float* bias = (const float*)d_in[4];
    float* out = (float*)d_out;

    // workspace layout
    char* ws = (char*)d_ws;
    unsigned short* xn  = (unsigned short*)(ws);                   //  8 MB  (bf16 NHWC)
    unsigned short* wt2 = (unsigned short*)(ws + (8u  << 20));     // 72 KB
    int*            di  = (int*)           (ws + (9u  << 20));     // ~2.4 MB
    float*          dw  = (float*)         (ws + (12u << 20));     // ~9.5 MB

    hipLaunchKernelGGL(prep, dim3(1168), dim3(256), 0, stream,
                       x, offs, mask, w, xn, wt2, di, dw);
    hipLaunchKernelGGL(dcn_main, dim3(1024), dim3(256), 0, stream,
                       xn, wt2, di, dw, bias, out);
}

// Round 7
// 45.368 us; speedup vs baseline: 5.4490x; 1.3489x over previous
//
#include <hip/hip_runtime.h>

#define BATCH 4
#define CIN 64
#define H 128
#define W 128
#define COUT 64
#define KK 9
#define HO 128
#define WO 128

typedef short bf16x8 __attribute__((ext_vector_type(8)));
typedef float f32x4 __attribute__((ext_vector_type(4)));

__device__ __forceinline__ unsigned short f2bf(float f) {
    unsigned u = __builtin_bit_cast(unsigned, f);
    u += 0x7FFFu + ((u >> 16) & 1u);          // RNE
    return (unsigned short)(u >> 16);
}
__device__ __forceinline__ float bflo(unsigned u) {   // low bf16 of dword
    return __builtin_bit_cast(float, u << 16);
}
__device__ __forceinline__ float bfhi(unsigned u) {   // high bf16 of dword
    return __builtin_bit_cast(float, u & 0xFFFF0000u);
}

// bilinear on one packed dword-column (2 channels), pack result to bf16x2
__device__ __forceinline__ unsigned bil_pack(unsigned u0, unsigned u1,
                                             unsigned u2, unsigned u3, f32x4 wv) {
    float lo = fmaf(wv[0], bflo(u0), fmaf(wv[1], bflo(u1),
               fmaf(wv[2], bflo(u2), wv[3] * bflo(u3))));
    float hi = fmaf(wv[0], bfhi(u0), fmaf(wv[1], bfhi(u1),
               fmaf(wv[2], bfhi(u2), wv[3] * bfhi(u3))));
    unsigned pk;
    asm("v_cvt_pk_bf16_f32 %0, %1, %2" : "=v"(pk) : "v"(lo), "v"(hi));
    return pk;
}

// Fused prep:
//  blocks 0..1023   : (b,oy,xh) NCHW->NHWC bf16 transpose + 576 sample descriptors
//  blocks 1024..1167: weight transpose  w[COUT][CIN][3][3] -> wt2[o][k*64+c] bf16
__global__ __launch_bounds__(256)
void prep(const float* __restrict__ x, const float* __restrict__ offs,
          const float* __restrict__ mask, const float* __restrict__ w,
          unsigned short* __restrict__ xn, unsigned short* __restrict__ wt2,
          int* __restrict__ di, float* __restrict__ dw) {
    const int blk = blockIdx.x;
    const int tid = threadIdx.x;

    if (blk >= 1024) {
        int g = (blk - 1024) * 256 + tid;     // 0..36863
        int o = g / 576;
        int rem = g - o * 576;
        int k = rem >> 6, c = rem & 63;
        wt2[g] = f2bf(w[(o * 64 + c) * 9 + k]);
        return;
    }

    const int b = blk >> 8, oy = (blk >> 1) & 127, xh = blk & 1;

    // ---- NHWC bf16 transpose for this 64-px row-half ----
    __shared__ float T[64][65];
    {
        const int px = tid & 63, cq = tid >> 6;
        const float* src = x + (((size_t)b * 64) << 14) + oy * 128 + xh * 64;
        #pragma unroll
        for (int j = 0; j < 16; ++j) {
            int c = cq * 16 + j;
            T[c][px] = src[((size_t)c << 14) + px];
        }
        __syncthreads();
        const int c2 = tid & 63, pq = tid >> 6;
        unsigned short* dst = xn + ((((size_t)b << 14) + oy * 128 + xh * 64) << 6) + c2;
        #pragma unroll
        for (int j = 0; j < 16; ++j) {
            int p = pq * 16 + j;
            dst[(size_t)p << 6] = f2bf(T[c2][p]);
        }
    }

    // ---- descriptors: one lane per sample point ----
    const int gbase = blk * 576;
    #pragma unroll
    for (int i = 0; i < 3; ++i) {
        int s = i * 256 + tid;
        if (s < 576) {
            int k = s >> 6, spx = s & 63;
            int ox = xh * 64 + spx;
            int kh = k / 3, kw = k - kh * 3;

            float offy = offs[((b * 18 + 2 * k    ) * 128 + oy) * 128 + ox];
            float offx = offs[((b * 18 + 2 * k + 1) * 128 + oy) * 128 + ox];
            float m    = mask[((b * 9  + k        ) * 128 + oy) * 128 + ox];

            float py  = (float)(oy - 1 + kh) + offy;
            float pxf = (float)(ox - 1 + kw) + offx;
            float fy = floorf(py), fx = floorf(pxf);
            float ly = py - fy, lx = pxf - fx;
            int y0 = (int)fy, x0 = (int)fx;
            int y1 = y0 + 1, x1 = x0 + 1;

            bool y0v = (y0 >= 0) & (y0 < H), y1v = (y1 >= 0) & (y1 < H);
            bool x0v = (x0 >= 0) & (x0 < W), x1v = (x1 >= 0) & (x1 < W);
            int y0c = min(max(y0, 0), H-1), y1c = min(max(y1, 0), H-1);
            int x0c = min(max(x0, 0), W-1), x1c = min(max(x1, 0), W-1);

            int p00 = (b << 14) + y0c * 128 + x0c;            // fits 16 bits
            int dx = x1c - x0c, dy = y1c - y0c;
            di[gbase + s] = p00 | (dx << 16) | (dy << 17);

            f32x4 wv;
            wv[0] = (1.f - ly) * (1.f - lx) * m * ((y0v & x0v) ? 1.f : 0.f);
            wv[1] = (1.f - ly) * lx         * m * ((y0v & x1v) ? 1.f : 0.f);
            wv[2] = ly         * (1.f - lx) * m * ((y1v & x0v) ? 1.f : 0.f);
            wv[3] = ly         * lx         * m * ((y1v & x1v) ? 1.f : 0.f);
            *(f32x4*)(dw + (size_t)(gbase + s) * 4) = wv;
        }
    }
}

__global__ __launch_bounds__(256, 4)
void dcn_main(const unsigned short* __restrict__ xn, const unsigned short* __restrict__ wt2,
              const int* __restrict__ di, const float* __restrict__ dw,
              const float* __restrict__ bias, float* __restrict__ out) {
    const int tid  = threadIdx.x;
    const int lane = tid & 63;
    const int wid  = tid >> 6;
    const int blk  = blockIdx.x;            // 2048
    const int p    = blk & 1;               // 32-px phase
    const int xh   = (blk >> 1) & 1;
    const int oy   = (blk >> 2) & 127;
    const int b    = blk >> 9;
    const int bo   = blk >> 1;              // prep-block id (0..1023)

    const int lg = lane >> 3;               // sample-in-group 0..7
    const int lc = lane & 7;                // channel-slice (channels lc*8..+7)

    __shared__ __align__(16) unsigned short S[32 * 576];   // 36 KB swizzled [pxl][r]
    const uint4* x4 = (const uint4*)xn;     // 16B view: row = px*8 uint4s

    const int sbase = bo * 576 + p * 32;
    const int gi0   = wid * 9;              // this wave's 9 groups (8 samples each)

    // ---- gather: dwordx4-packed corners, parity-prefetched descriptors ----
    #define LOADDESC(GI, D, WV)                                            \
    {   int si = sbase + (((GI) >> 2) << 6) + (((GI) & 3) << 3) + lg;      \
        D  = di[si];                                                       \
        WV = *(const f32x4*)(dw + (size_t)si * 4);                         \
    }
    #define PROCESS(GI, D, WV)                                             \
    {   int k_  = (GI) >> 2;                                               \
        int pxl = (((GI) & 3) << 3) + lg;                                  \
        unsigned p00   = (unsigned)(D) & 0xFFFFu;                          \
        unsigned base4 = (p00 << 3) + (unsigned)lc;                        \
        unsigned o01   = (((unsigned)(D) >> 16) & 1u) << 3;                \
        unsigned o10   = (((unsigned)(D) >> 17) & 1u) << 10;               \
        uint4 c00 = x4[base4];                                             \
        uint4 c01 = x4[base4 + o01];                                       \
        uint4 c10 = x4[base4 + o10];                                       \
        uint4 c11 = x4[base4 + o01 + o10];                                 \
        uint4 pk;                                                          \
        pk.x = bil_pack(c00.x, c01.x, c10.x, c11.x, WV);                   \
        pk.y = bil_pack(c00.y, c01.y, c10.y, c11.y, WV);                   \
        pk.z = bil_pack(c00.z, c01.z, c10.z, c11.z, WV);                   \
        pk.w = bil_pack(c00.w, c01.w, c10.w, c11.w, WV);                   \
        int sb = pxl * 1152 + k_ * 128 + ((lc * 16) ^ ((pxl & 7) << 4));   \
        *(uint4*)((char*)S + sb) = pk;                                     \
    }

    int dA, dB; f32x4 wA, wB;
    LOADDESC(gi0, dA, wA)
    #pragma unroll 1
    for (int gg = 0; gg < 4; ++gg) {
        LOADDESC(gi0 + 2 * gg + 1, dB, wB)
        PROCESS(gi0 + 2 * gg, dA, wA)
        LOADDESC(gi0 + 2 * gg + 2, dA, wA)
        PROCESS(gi0 + 2 * gg + 1, dB, wB)
    }
    PROCESS(gi0 + 8, dA, wA)
    #undef PROCESS
    #undef LOADDESC
    __syncthreads();

    // ---- MFMA sweep, K = 576, afrag depth-1 prefetched from L2-hot wt2 ----
    f32x4 acc0 = {}, acc1 = {};
    {
        int o = wid * 16 + (lane & 15);
        const unsigned short* wp = wt2 + o * 576 + (lane >> 4) * 8;
        const int pxr0 = lane & 15;
        const int rb   = (lane >> 4) * 16;            // byte col base
        const int swz0 = (pxr0 & 7) << 4;
        const int bo0base = pxr0 * 1152;
        const int bo1base = (pxr0 + 16) * 1152;

        bf16x8 afA = *(const bf16x8*)(wp);
        bf16x8 afB;
        #pragma unroll 1
        for (int ss = 0; ss < 9; ++ss) {
            afB = *(const bf16x8*)(wp + (2 * ss + 1) * 32);
            {
                int colx = (2 * ss * 64 + rb) ^ swz0;
                bf16x8 b0 = *(const bf16x8*)((const char*)S + bo0base + colx);
                bf16x8 b1 = *(const bf16x8*)((const char*)S + bo1base + colx);
                acc0 = __builtin_amdgcn_mfma_f32_16x16x32_bf16(afA, b0, acc0, 0, 0, 0);
                acc1 = __builtin_amdgcn_mfma_f32_16x16x32_bf16(afA, b1, acc1, 0, 0, 0);
            }
            if (ss < 8) afA = *(const bf16x8*)(wp + (2 * ss + 2) * 32);
            {
                int colx = ((2 * ss + 1) * 64 + rb) ^ swz0;
                bf16x8 b0 = *(const bf16x8*)((const char*)S + bo0base + colx);
                bf16x8 b1 = *(const bf16x8*)((const char*)S + bo1base + colx);
                acc0 = __builtin_amdgcn_mfma_f32_16x16x32_bf16(afB, b0, acc0, 0, 0, 0);
                acc1 = __builtin_amdgcn_mfma_f32_16x16x32_bf16(afB, b1, acc1, 0, 0, 0);
            }
        }
    }

    // ---- epilogue for this block's 32 pixels ----
    const int q0 = (lane >> 4) * 4;
    #pragma unroll
    for (int q = 0; q < 4; ++q) {
        int o   = wid * 16 + q0 + q;
        int oxb = xh * 64 + p * 32 + (lane & 15);
        float* dst = out + (((size_t)(b * 64 + o)) * 128 + oy) * 128 + oxb;
        dst[0]  = acc0[q] + bias[o];
        dst[16] = acc1[q] + bias[o];
    }
}

extern "C" void kernel_launch(void* const* d_in, const int* in_sizes, int n_in,
                              void* d_out, int out_size, void* d_ws, size_t ws_size,
                              hipStream_t stream) {
    const float* x    = (const float*)d_in[0];
    const float* offs = (const float*)d_in[1];
    const float* mask = (const float*)d_in[2];
    const float* w    = (const float*)d_in[3];
    const float* bias = (const float*)d_in[4];
    float* out = (float*)d_out;

    // workspace layout
    char* ws = (char*)d_ws;
    unsigned short* xn  = (unsigned short*)(ws);                   //  8 MB  (bf16 NHWC)
    unsigned short* wt2 = (unsigned short*)(ws + (8u  << 20));     // 72 KB
    int*            di  = (int*)           (ws + (9u  << 20));     // ~2.4 MB
    float*          dw  = (float*)         (ws + (12u << 20));     // ~9.5 MB

    hipLaunchKernelGGL(prep, dim3(1168), dim3(256), 0, stream,
                       x, offs, mask, w, xn, wt2, di, dw);
    hipLaunchKernelGGL(dcn_main, dim3(2048), dim3(256), 0, stream,
                       xn, wt2, di, dw, bias, out);
}